// Round 1
// baseline (1145.200 us; speedup 1.0000x reference)
//
#include <hip/hip_runtime.h>

// LoraLinear: out[t][i][j] = sum_k x[i][k]*W[j][k] + bias[j]
//                          + sum_r ( sum_k x[i][k]*A[ti][r][k] ) * Bm[ti][j][r]
// i = b*S+s in [0,16384), j in [0,1024), t in [0,4), ti = tuner_index[t]

namespace {
constexpr int kM    = 4 * 4096;   // B*S = 16384
constexpr int kDin  = 1024;
constexpr int kDout = 1024;
constexpr int kR    = 16;
constexpr int kT    = 4;

constexpr int BM = 128, BN = 128, BK = 16;
}  // namespace

// ---------------------------------------------------------------------------
// Kernel A: low[t][i][r] = x[i][:] . A[tuner[t]][r][:]
// One wave per row; lane -> (t = lane>>4, r = lane&15). x row is wave-uniform
// (broadcast loads); each lane streams its own A row (L1/L2-resident, 256 KB).
// ---------------------------------------------------------------------------
__global__ __launch_bounds__(256) void lora_low(const float* __restrict__ x,
                                                const float* __restrict__ A,
                                                const int* __restrict__ tuner,
                                                float* __restrict__ low) {
  const int lane = threadIdx.x & 63;
  const int wid  = threadIdx.x >> 6;
  const int row  = blockIdx.x * 4 + wid;
  const int t    = lane >> 4;
  const int r    = lane & 15;
  const int ti   = tuner[t];
  const float4* __restrict__ ar = (const float4*)(A + ((size_t)ti * kR + r) * kDin);
  const float4* __restrict__ xr = (const float4*)(x + (size_t)row * kDin);
  float acc = 0.f;
#pragma unroll 8
  for (int q = 0; q < kDin / 4; ++q) {
    const float4 a = ar[q];
    const float4 v = xr[q];
    acc += a.x * v.x + a.y * v.y + a.z * v.z + a.w * v.w;
  }
  low[((size_t)t * kM + row) * kR + r] = acc;
}

// ---------------------------------------------------------------------------
// Kernel B: tiled fp32 GEMM (128x128x16, 256 thr, 8x8 microtile) + per-t
// rank-16 epilogue + bias, writing all 4 adapter output slabs from one base
// accumulation.
// LDS is k-major ([BK][BM+4]) so microkernel reads are float4 with only
// broadcast / mild 4-way patterns.
// ---------------------------------------------------------------------------
__global__ __launch_bounds__(256) void lora_main(const float* __restrict__ x,
                                                 const float* __restrict__ W,
                                                 const float* __restrict__ bias,
                                                 const float* __restrict__ Bm,
                                                 const int* __restrict__ tuner,
                                                 const float* __restrict__ low,
                                                 float* __restrict__ out) {
  __shared__ float As[BK][BM + 4];   // x tile, k-major
  __shared__ float Bs[BK][BN + 4];   // W tile, k-major
  __shared__ float Ls[BM][kR + 1];   // low tile (row-major, pad 17)
  __shared__ float Ms[kR][BN + 4];   // Bm tile, r-major

  const int tid = threadIdx.x;
  const int tx  = tid & 15;
  const int ty  = tid >> 4;
  const int j0  = blockIdx.x * BN;
  const int i0  = blockIdx.y * BM;

  float acc[8][8];
#pragma unroll
  for (int a = 0; a < 8; ++a)
#pragma unroll
    for (int b = 0; b < 8; ++b) acc[a][b] = 0.f;

  for (int kt = 0; kt < kDin; kt += BK) {
    // Stage As/Bs: 512 float4 each; f -> (row i = f>>2, k-quad = f&3).
#pragma unroll
    for (int p = 0; p < 2; ++p) {
      const int f  = tid + p * 256;
      const int i  = f >> 2;
      const int kq = (f & 3) * 4;
      const float4 v = *(const float4*)(x + (size_t)(i0 + i) * kDin + kt + kq);
      As[kq + 0][i] = v.x; As[kq + 1][i] = v.y; As[kq + 2][i] = v.z; As[kq + 3][i] = v.w;
      const float4 w = *(const float4*)(W + (size_t)(j0 + i) * kDin + kt + kq);
      Bs[kq + 0][i] = w.x; Bs[kq + 1][i] = w.y; Bs[kq + 2][i] = w.z; Bs[kq + 3][i] = w.w;
    }
    __syncthreads();
#pragma unroll
    for (int k = 0; k < BK; ++k) {
      const float4 a0 = *(const float4*)&As[k][ty * 8];
      const float4 a1 = *(const float4*)&As[k][ty * 8 + 4];
      const float4 b0 = *(const float4*)&Bs[k][tx * 8];
      const float4 b1 = *(const float4*)&Bs[k][tx * 8 + 4];
      const float av[8] = {a0.x, a0.y, a0.z, a0.w, a1.x, a1.y, a1.z, a1.w};
      const float bw[8] = {b0.x, b0.y, b0.z, b0.w, b1.x, b1.y, b1.z, b1.w};
#pragma unroll
      for (int ii = 0; ii < 8; ++ii)
#pragma unroll
        for (int jj = 0; jj < 8; ++jj) acc[ii][jj] += av[ii] * bw[jj];
    }
    __syncthreads();
  }

  float bv[8];
#pragma unroll
  for (int jj = 0; jj < 8; ++jj) bv[jj] = bias[j0 + tx * 8 + jj];

  for (int t = 0; t < kT; ++t) {
    __syncthreads();  // previous t's Ls/Ms reads done before restaging
    const int ti = tuner[t];
#pragma unroll
    for (int p = 0; p < 2; ++p) {
      const int f  = tid + p * 256;
      const int i  = f >> 2;
      const int rq = (f & 3) * 4;
      const float4 lv = *(const float4*)(low + ((size_t)t * kM + i0 + i) * kR + rq);
      Ls[i][rq + 0] = lv.x; Ls[i][rq + 1] = lv.y; Ls[i][rq + 2] = lv.z; Ls[i][rq + 3] = lv.w;
      const float4 mv = *(const float4*)(Bm + ((size_t)ti * kDout + j0 + i) * kR + rq);
      Ms[rq + 0][i] = mv.x; Ms[rq + 1][i] = mv.y; Ms[rq + 2][i] = mv.z; Ms[rq + 3][i] = mv.w;
    }
    __syncthreads();

    float d[8][8];
#pragma unroll
    for (int ii = 0; ii < 8; ++ii)
#pragma unroll
      for (int jj = 0; jj < 8; ++jj) d[ii][jj] = acc[ii][jj] + bv[jj];

#pragma unroll
    for (int r = 0; r < kR; ++r) {
      const float4 m0 = *(const float4*)&Ms[r][tx * 8];
      const float4 m1 = *(const float4*)&Ms[r][tx * 8 + 4];
      const float mv[8] = {m0.x, m0.y, m0.z, m0.w, m1.x, m1.y, m1.z, m1.w};
      float la[8];
#pragma unroll
      for (int ii = 0; ii < 8; ++ii) la[ii] = Ls[ty * 8 + ii][r];
#pragma unroll
      for (int ii = 0; ii < 8; ++ii)
#pragma unroll
        for (int jj = 0; jj < 8; ++jj) d[ii][jj] += la[ii] * mv[jj];
    }

#pragma unroll
    for (int ii = 0; ii < 8; ++ii) {
      const size_t o = ((size_t)t * kM + i0 + ty * 8 + ii) * kDout + j0 + tx * 8;
      *(float4*)(out + o)     = make_float4(d[ii][0], d[ii][1], d[ii][2], d[ii][3]);
      *(float4*)(out + o + 4) = make_float4(d[ii][4], d[ii][5], d[ii][6], d[ii][7]);
    }
  }
}

// ---------------------------------------------------------------------------
extern "C" void kernel_launch(void* const* d_in, const int* in_sizes, int n_in,
                              void* d_out, int out_size, void* d_ws, size_t ws_size,
                              hipStream_t stream) {
  const float* x    = (const float*)d_in[0];
  const float* W    = (const float*)d_in[1];
  const float* bias = (const float*)d_in[2];
  const float* lA   = (const float*)d_in[3];
  const float* lB   = (const float*)d_in[4];
  const int*   ti   = (const int*)d_in[5];
  float* out = (float*)d_out;
  float* low = (float*)d_ws;  // needs kT*kM*kR*4 = 4 MiB of scratch

  lora_low<<<kM / 4, 256, 0, stream>>>(x, lA, ti, low);
  lora_main<<<dim3(kDout / BN, kM / BM), 256, 0, stream>>>(x, W, bias, lB, ti, low, out);
}

// Round 3
// 388.973 us; speedup vs baseline: 2.9442x; 2.9442x over previous
//
#include <hip/hip_runtime.h>

// out[t][i][j] = sum_k x[i][k]*W[j][k] + bias[j] + sum_r low[t][i][r]*Bm[ti][j][r]
// low[t][i][r] = sum_k x[i][k]*A[ti][r][k]
// Base GEMM via split-bf16 MFMA: x*W ~= xh*Wh + xh*Wl + xl*Wh (fp32 accum).

typedef __attribute__((ext_vector_type(8))) short short8;
typedef __attribute__((ext_vector_type(4))) float f32x4;
typedef __attribute__((ext_vector_type(4))) unsigned short us4;
typedef __attribute__((ext_vector_type(8))) unsigned short us8;

namespace {
constexpr int kM = 16384, kDin = 1024, kDout = 1024, kR = 16, kT = 4;
// d_ws byte offsets
constexpr size_t OFF_XH  = 0;               // [16384][1024] bf16 = 32 MiB
constexpr size_t OFF_XL  = 33554432;        // 32 MiB
constexpr size_t OFF_WH  = 67108864;        // [1024][1024] bf16 = 2 MiB
constexpr size_t OFF_WL  = 69206016;        // 2 MiB
constexpr size_t OFF_LOW = 71303168;        // [4][16384][16] bf16 = 2 MiB
}

__device__ inline unsigned short f2bf(float f) {
  unsigned int u = __float_as_uint(f);
  u += 0x7fff + ((u >> 16) & 1);  // RNE
  return (unsigned short)(u >> 16);
}
__device__ inline float bf2f(unsigned short h) {
  return __uint_as_float(((unsigned int)h) << 16);
}
__device__ inline void gload_lds16(const void* g, void* l) {
  __builtin_amdgcn_global_load_lds(
      (const __attribute__((address_space(1))) unsigned int*)g,
      (__attribute__((address_space(3))) unsigned int*)l, 16, 0, 0);
}
__device__ inline f32x4 mfma_bf16(short8 a, short8 b, f32x4 c) {
  return __builtin_amdgcn_mfma_f32_16x16x32_bf16(a, b, c, 0, 0, 0);
}

// ---------------------------------------------------------------------------
// Kernel 1: fp32 -> bf16 hi/lo split for x and W.
// ---------------------------------------------------------------------------
__global__ __launch_bounds__(256) void cvt_hilo(const float* __restrict__ x,
                                                const float* __restrict__ W,
                                                unsigned short* __restrict__ xh,
                                                unsigned short* __restrict__ xl,
                                                unsigned short* __restrict__ wh,
                                                unsigned short* __restrict__ wl) {
  constexpr int NX4 = kM * kDin / 4;      // 4194304
  constexpr int NW4 = kDout * kDin / 4;   // 262144
  const int stride = gridDim.x * blockDim.x;
  for (int i = blockIdx.x * blockDim.x + threadIdx.x; i < NX4 + NW4; i += stride) {
    const bool isx = i < NX4;
    const int  j   = isx ? i : i - NX4;
    const float4 v = isx ? ((const float4*)x)[j] : ((const float4*)W)[j];
    const float e[4] = {v.x, v.y, v.z, v.w};
    us4 h, l;
#pragma unroll
    for (int q = 0; q < 4; ++q) {
      h[q] = f2bf(e[q]);
      l[q] = f2bf(e[q] - bf2f(h[q]));
    }
    if (isx) { ((us4*)xh)[j] = h; ((us4*)xl)[j] = l; }
    else     { ((us4*)wh)[j] = h; ((us4*)wl)[j] = l; }
  }
}

// ---------------------------------------------------------------------------
// Kernel 2: low[t][i][r] = x[i][:] . A[tuner[t]][r][:]  -> bf16
// Tiled skinny GEMM: BM=32 rows, N=64 (t,r), BK=64, fully coalesced loads.
// ---------------------------------------------------------------------------
__global__ __launch_bounds__(256) void lora_low(const float* __restrict__ x,
                                                const float* __restrict__ A,
                                                const int* __restrict__ tuner,
                                                unsigned short* __restrict__ lowb) {
  __shared__ float xs[64][34];  // [k][row]
  __shared__ float as[64][66];  // [k][t*16+r]
  const int tid = threadIdx.x;
  const int i0  = blockIdx.x * 32;
  const int tx  = tid & 15;   // col group (4 cols)
  const int ty  = tid >> 4;   // row group (2 rows)
  float acc[2][4] = {{0.f, 0.f, 0.f, 0.f}, {0.f, 0.f, 0.f, 0.f}};

  for (int kt = 0; kt < kDin; kt += 64) {
    __syncthreads();
#pragma unroll
    for (int p = 0; p < 2; ++p) {  // x tile: 32 rows x 64 k
      const int f = tid + p * 256;
      const int row = f >> 4, kq = (f & 15) * 4;
      const float4 v = *(const float4*)(x + (size_t)(i0 + row) * kDin + kt + kq);
      xs[kq + 0][row] = v.x; xs[kq + 1][row] = v.y;
      xs[kq + 2][row] = v.z; xs[kq + 3][row] = v.w;
    }
#pragma unroll
    for (int p = 0; p < 4; ++p) {  // A tile: 64 (t,r) rows x 64 k
      const int f = tid + p * 256;
      const int ar = f >> 4, kq = (f & 15) * 4;
      const int ti = tuner[ar >> 4];
      const float4 v = *(const float4*)(A + ((size_t)ti * kR + (ar & 15)) * kDin + kt + kq);
      as[kq + 0][ar] = v.x; as[kq + 1][ar] = v.y;
      as[kq + 2][ar] = v.z; as[kq + 3][ar] = v.w;
    }
    __syncthreads();
#pragma unroll 8
    for (int k = 0; k < 64; ++k) {
      const float a0 = xs[k][ty * 2], a1 = xs[k][ty * 2 + 1];
      const float b0 = as[k][tx * 4], b1 = as[k][tx * 4 + 1];
      const float b2 = as[k][tx * 4 + 2], b3 = as[k][tx * 4 + 3];
      acc[0][0] += a0 * b0; acc[0][1] += a0 * b1; acc[0][2] += a0 * b2; acc[0][3] += a0 * b3;
      acc[1][0] += a1 * b0; acc[1][1] += a1 * b1; acc[1][2] += a1 * b2; acc[1][3] += a1 * b3;
    }
  }
  // col c = tx*4+j  ->  t = tx>>2, r = (tx&3)*4+j
#pragma unroll
  for (int ii = 0; ii < 2; ++ii) {
    us4 o;
#pragma unroll
    for (int j = 0; j < 4; ++j) o[j] = f2bf(acc[ii][j]);
    *(us4*)(lowb + ((size_t)(tx >> 2) * kM + i0 + ty * 2 + ii) * kR + (tx & 3) * 4) = o;
  }
}

// ---------------------------------------------------------------------------
// Kernel 3: main MFMA GEMM (128x128 tile, BK=32) + per-t rank-16 MFMA epilogue.
// LDS layout per buffer: [kgrp(4)][row(128)][16B] -> conflict-free ds_read_b128.
// Wave w stages buffer w (xh,xl,wh,wl). Waves 2x2 over the 128x128 tile.
// ---------------------------------------------------------------------------
__global__ __launch_bounds__(256) void lora_main(
    const unsigned short* __restrict__ xh, const unsigned short* __restrict__ xl,
    const unsigned short* __restrict__ wh, const unsigned short* __restrict__ wl,
    const float* __restrict__ bias, const float* __restrict__ Bm,
    const int* __restrict__ tuner, const unsigned short* __restrict__ lowb,
    float* __restrict__ out) {
  __shared__ __align__(16) unsigned char smem[32768];
  const int tid  = threadIdx.x;
  const int lane = tid & 63;
  const int w    = tid >> 6;

  // XCD swizzle (1024 blocks, %8==0 -> simple form is bijective)
  const int swz = (blockIdx.x & 7) * 128 + (blockIdx.x >> 3);
  const int bm = swz >> 3, bn = swz & 7;
  const size_t i0 = (size_t)bm * 128, j0 = (size_t)bn * 128;
  const int wm = w >> 1, wn = w & 1;

  const unsigned short* gsrc = (w == 0) ? xh : (w == 1) ? xl : (w == 2) ? wh : wl;
  const size_t grow0 = (w < 2) ? i0 : j0;
  unsigned char* bufbase = smem + (size_t)w * 8192;

  f32x4 acc[4][4];
#pragma unroll
  for (int m = 0; m < 4; ++m)
#pragma unroll
    for (int n = 0; n < 4; ++n) acc[m][n] = (f32x4){0.f, 0.f, 0.f, 0.f};

  const int kg = lane >> 4;   // k-group 0..3
  const int rl = lane & 15;

  for (int kt = 0; kt < kDin; kt += 32) {
    // stage this wave's buffer: 8 x global_load_lds(16B); LDS linear idx*16,
    // idx = kgrp*128 + row  (pre-swizzled global source keeps LDS linear)
#pragma unroll
    for (int c = 0; c < 8; ++c) {
      const int idx = c * 64 + lane;
      const int row = idx & 127, g = idx >> 7;
      gload_lds16(gsrc + (grow0 + row) * kDin + kt + g * 8, bufbase + c * 1024);
    }
    __syncthreads();

    short8 ah[4], al[4], bh[4], bl[4];
#pragma unroll
    for (int m = 0; m < 4; ++m) {
      const int rowA = wm * 64 + m * 16 + rl;
      const int rowB = wn * 64 + m * 16 + rl;
      ah[m] = *(const short8*)(smem +         kg * 2048 + rowA * 16);
      al[m] = *(const short8*)(smem +  8192 + kg * 2048 + rowA * 16);
      bh[m] = *(const short8*)(smem + 16384 + kg * 2048 + rowB * 16);
      bl[m] = *(const short8*)(smem + 24576 + kg * 2048 + rowB * 16);
    }
#pragma unroll
    for (int m = 0; m < 4; ++m)
#pragma unroll
      for (int n = 0; n < 4; ++n) {
        acc[m][n] = mfma_bf16(ah[m], bh[n], acc[m][n]);
        acc[m][n] = mfma_bf16(ah[m], bl[n], acc[m][n]);
        acc[m][n] = mfma_bf16(al[m], bh[n], acc[m][n]);
      }
    __syncthreads();
  }

  // pre-add bias into acc (col depends only on lane)
  float bv[4];
#pragma unroll
  for (int n = 0; n < 4; ++n) bv[n] = bias[j0 + wn * 64 + n * 16 + rl];
#pragma unroll
  for (int m = 0; m < 4; ++m)
#pragma unroll
    for (int n = 0; n < 4; ++n)
#pragma unroll
      for (int r = 0; r < 4; ++r) acc[m][n][r] += bv[n];

  // zero the K=16..31 pad of the epilogue tiles: Lt kgrp2-3 = smem[4096:8192),
  // Mt kgrp2-3 = smem[12288:16384)
  {
    unsigned char* p = (tid < 128) ? (smem + 4096 + tid * 32)
                                   : (smem + 12288 + (tid - 128) * 32);
    const us8 z = {0, 0, 0, 0, 0, 0, 0, 0};
    *(us8*)p = z;
    *(us8*)(p + 16) = z;
  }

  for (int t = 0; t < kT; ++t) {
    __syncthreads();  // zeros visible / previous t's reads done
    {
      const int row = tid >> 1, half = tid & 1;
      // Lt (low tile, bf16): smem[0:4096) kgrp 0-1
      const us8 lv = *(const us8*)(lowb + ((size_t)t * kM + i0 + row) * kR + half * 8);
      *(us8*)(smem + half * 2048 + row * 16) = lv;
      // Mt (Bm tile, fp32 -> bf16): smem[8192:12288) kgrp 0-1
      const int ti = tuner[t];
      const float* bp = Bm + ((size_t)ti * kDout + j0 + row) * kR + half * 8;
      const float4 m0 = *(const float4*)bp;
      const float4 m1 = *(const float4*)(bp + 4);
      us8 mv;
      mv[0] = f2bf(m0.x); mv[1] = f2bf(m0.y); mv[2] = f2bf(m0.z); mv[3] = f2bf(m0.w);
      mv[4] = f2bf(m1.x); mv[5] = f2bf(m1.y); mv[6] = f2bf(m1.z); mv[7] = f2bf(m1.w);
      *(us8*)(smem + 8192 + half * 2048 + row * 16) = mv;
    }
    __syncthreads();

    short8 lf[4], mf[4];
#pragma unroll
    for (int m = 0; m < 4; ++m)
      lf[m] = *(const short8*)(smem + kg * 2048 + (wm * 64 + m * 16 + rl) * 16);
#pragma unroll
    for (int n = 0; n < 4; ++n)
      mf[n] = *(const short8*)(smem + 8192 + kg * 2048 + (wn * 64 + n * 16 + rl) * 16);

#pragma unroll
    for (int m = 0; m < 4; ++m)
#pragma unroll
      for (int n = 0; n < 4; ++n) {
        const f32x4 d = mfma_bf16(lf[m], mf[n], acc[m][n]);
        const int r4  = wm * 64 + m * 16 + kg * 4;
        const int col = (int)j0 + wn * 64 + n * 16 + rl;
        const size_t base = ((size_t)t * kM + i0 + r4) * kDout + col;
        out[base]             = d[0];
        out[base + kDout]     = d[1];
        out[base + 2 * kDout] = d[2];
        out[base + 3 * kDout] = d[3];
      }
  }
}

// ---------------------------------------------------------------------------
extern "C" void kernel_launch(void* const* d_in, const int* in_sizes, int n_in,
                              void* d_out, int out_size, void* d_ws, size_t ws_size,
                              hipStream_t stream) {
  const float* x    = (const float*)d_in[0];
  const float* W    = (const float*)d_in[1];
  const float* bias = (const float*)d_in[2];
  const float* lA   = (const float*)d_in[3];
  const float* lB   = (const float*)d_in[4];
  const int*   ti   = (const int*)d_in[5];
  float* out = (float*)d_out;

  unsigned char* ws = (unsigned char*)d_ws;
  unsigned short* xh   = (unsigned short*)(ws + OFF_XH);
  unsigned short* xl   = (unsigned short*)(ws + OFF_XL);
  unsigned short* wh   = (unsigned short*)(ws + OFF_WH);
  unsigned short* wl   = (unsigned short*)(ws + OFF_WL);
  unsigned short* lowb = (unsigned short*)(ws + OFF_LOW);

  cvt_hilo<<<1024, 256, 0, stream>>>(x, W, xh, xl, wh, wl);
  lora_low<<<kM / 32, 256, 0, stream>>>(x, lA, ti, lowb);
  lora_main<<<1024, 256, 0, stream>>>(xh, xl, wh, wl, bias, lB, ti, lowb, out);
}

// Round 4
// 223.835 us; speedup vs baseline: 5.1163x; 1.7378x over previous
//
#include <hip/hip_runtime.h>

// out[t][i][j] = sum_k x[i][k]*W[j][k] + bias[j] + sum_r low[t][i][r]*Bm[ti][j][r]
// low[t][i][r] = sum_k x[i][k]*A[ti][r][k]
// Base GEMM via split-bf16 MFMA: x*W ~= xh*Wh + xh*Wl + xl*Wh (fp32 accum).

typedef __attribute__((ext_vector_type(8))) short short8;
typedef __attribute__((ext_vector_type(4))) float f32x4;
typedef __attribute__((ext_vector_type(4))) unsigned short us4;
typedef __attribute__((ext_vector_type(8))) unsigned short us8;

namespace {
constexpr int kM = 16384, kDin = 1024, kDout = 1024, kR = 16, kT = 4;
// d_ws byte offsets
constexpr size_t OFF_XH  = 0;               // [16384][1024] bf16 = 32 MiB
constexpr size_t OFF_XL  = 33554432;        // 32 MiB
constexpr size_t OFF_WH  = 67108864;        // [1024][1024] bf16 = 2 MiB
constexpr size_t OFF_WL  = 69206016;        // 2 MiB
constexpr size_t OFF_LOW = 71303168;        // [4][16384][16] bf16 = 2 MiB
}

__device__ inline unsigned short f2bf(float f) {
  unsigned int u = __float_as_uint(f);
  u += 0x7fff + ((u >> 16) & 1);  // RNE
  return (unsigned short)(u >> 16);
}
__device__ inline float bf2f(unsigned short h) {
  return __uint_as_float(((unsigned int)h) << 16);
}
__device__ inline void gload_lds16(const void* g, void* l) {
  __builtin_amdgcn_global_load_lds(
      (const __attribute__((address_space(1))) unsigned int*)g,
      (__attribute__((address_space(3))) unsigned int*)l, 16, 0, 0);
}
__device__ inline f32x4 mfma_bf16(short8 a, short8 b, f32x4 c) {
  return __builtin_amdgcn_mfma_f32_16x16x32_bf16(a, b, c, 0, 0, 0);
}

// ---------------------------------------------------------------------------
// Kernel 1: fp32 -> bf16 hi/lo split for x and W.  (unchanged from round 3)
// ---------------------------------------------------------------------------
__global__ __launch_bounds__(256) void cvt_hilo(const float* __restrict__ x,
                                                const float* __restrict__ W,
                                                unsigned short* __restrict__ xh,
                                                unsigned short* __restrict__ xl,
                                                unsigned short* __restrict__ wh,
                                                unsigned short* __restrict__ wl) {
  constexpr int NX4 = kM * kDin / 4;      // 4194304
  constexpr int NW4 = kDout * kDin / 4;   // 262144
  const int stride = gridDim.x * blockDim.x;
  for (int i = blockIdx.x * blockDim.x + threadIdx.x; i < NX4 + NW4; i += stride) {
    const bool isx = i < NX4;
    const int  j   = isx ? i : i - NX4;
    const float4 v = isx ? ((const float4*)x)[j] : ((const float4*)W)[j];
    const float e[4] = {v.x, v.y, v.z, v.w};
    us4 h, l;
#pragma unroll
    for (int q = 0; q < 4; ++q) {
      h[q] = f2bf(e[q]);
      l[q] = f2bf(e[q] - bf2f(h[q]));
    }
    if (isx) { ((us4*)xh)[j] = h; ((us4*)xl)[j] = l; }
    else     { ((us4*)wh)[j] = h; ((us4*)wl)[j] = l; }
  }
}

// ---------------------------------------------------------------------------
// Kernel 2: low[t][i][r] = x[i][:] . A[tuner[t]][r][:]  -> bf16
// (unchanged from round 3)
// ---------------------------------------------------------------------------
__global__ __launch_bounds__(256) void lora_low(const float* __restrict__ x,
                                                const float* __restrict__ A,
                                                const int* __restrict__ tuner,
                                                unsigned short* __restrict__ lowb) {
  __shared__ float xs[64][34];  // [k][row]
  __shared__ float as[64][66];  // [k][t*16+r]
  const int tid = threadIdx.x;
  const int i0  = blockIdx.x * 32;
  const int tx  = tid & 15;   // col group (4 cols)
  const int ty  = tid >> 4;   // row group (2 rows)
  float acc[2][4] = {{0.f, 0.f, 0.f, 0.f}, {0.f, 0.f, 0.f, 0.f}};

  for (int kt = 0; kt < kDin; kt += 64) {
    __syncthreads();
#pragma unroll
    for (int p = 0; p < 2; ++p) {  // x tile: 32 rows x 64 k
      const int f = tid + p * 256;
      const int row = f >> 4, kq = (f & 15) * 4;
      const float4 v = *(const float4*)(x + (size_t)(i0 + row) * kDin + kt + kq);
      xs[kq + 0][row] = v.x; xs[kq + 1][row] = v.y;
      xs[kq + 2][row] = v.z; xs[kq + 3][row] = v.w;
    }
#pragma unroll
    for (int p = 0; p < 4; ++p) {  // A tile: 64 (t,r) rows x 64 k
      const int f = tid + p * 256;
      const int ar = f >> 4, kq = (f & 15) * 4;
      const int ti = tuner[ar >> 4];
      const float4 v = *(const float4*)(A + ((size_t)ti * kR + (ar & 15)) * kDin + kt + kq);
      as[kq + 0][ar] = v.x; as[kq + 1][ar] = v.y;
      as[kq + 2][ar] = v.z; as[kq + 3][ar] = v.w;
    }
    __syncthreads();
#pragma unroll 8
    for (int k = 0; k < 64; ++k) {
      const float a0 = xs[k][ty * 2], a1 = xs[k][ty * 2 + 1];
      const float b0 = as[k][tx * 4], b1 = as[k][tx * 4 + 1];
      const float b2 = as[k][tx * 4 + 2], b3 = as[k][tx * 4 + 3];
      acc[0][0] += a0 * b0; acc[0][1] += a0 * b1; acc[0][2] += a0 * b2; acc[0][3] += a0 * b3;
      acc[1][0] += a1 * b0; acc[1][1] += a1 * b1; acc[1][2] += a1 * b2; acc[1][3] += a1 * b3;
    }
  }
  // col c = tx*4+j  ->  t = tx>>2, r = (tx&3)*4+j
#pragma unroll
  for (int ii = 0; ii < 2; ++ii) {
    us4 o;
#pragma unroll
    for (int j = 0; j < 4; ++j) o[j] = f2bf(acc[ii][j]);
    *(us4*)(lowb + ((size_t)(tx >> 2) * kM + i0 + ty * 2 + ii) * kR + (tx & 3) * 4) = o;
  }
}

// ---------------------------------------------------------------------------
// Kernel 3: main MFMA GEMM (128x128 tile, BK=32) + per-t rank-16 MFMA epilogue.
// v2 changes vs round 3:
//  - LDS tiles are row-major [mat][row(128)][32k = 64B]: staging lane-map
//    row = g>>2, chunk = g&3 -> each gload_lds reads 16 contiguous 64B
//    segments (coalesced; was 64 scattered lines).  ds_read_b128 fragment at
//    row*64 + kg*16 is uniform 8 lanes/bank-group = conflict-free floor.
//  - Double-buffered (2 x 32KB) 2-phase pipeline: prefetch K-step s+1 before
//    computing step s; one barrier per step hides staging latency.
//  - s_setprio(1) around the MFMA cluster.
// Epilogue identical to round 3 (verified), placed in buf0's region.
// ---------------------------------------------------------------------------
__global__ __launch_bounds__(256) void lora_main(
    const unsigned short* __restrict__ xh, const unsigned short* __restrict__ xl,
    const unsigned short* __restrict__ wh, const unsigned short* __restrict__ wl,
    const float* __restrict__ bias, const float* __restrict__ Bm,
    const int* __restrict__ tuner, const unsigned short* __restrict__ lowb,
    float* __restrict__ out) {
  __shared__ __align__(16) unsigned char smem[65536];
  const int tid  = threadIdx.x;
  const int lane = tid & 63;
  const int w    = tid >> 6;

  // XCD swizzle (1024 blocks, %8==0 -> simple form is bijective)
  const int swz = ((int)blockIdx.x & 7) * 128 + ((int)blockIdx.x >> 3);
  const int bm = swz >> 3, bn = swz & 7;
  const size_t i0 = (size_t)bm * 128, j0 = (size_t)bn * 128;
  const int wm = w >> 1, wn = w & 1;

  // staging source for this wave (wave w stages matrix w)
  const unsigned short* gsrc = (w == 0) ? xh : (w == 1) ? xl : (w == 2) ? wh : wl;
  const size_t grow0 = (w < 2) ? i0 : j0;
  // per-lane global offset: row = lane>>2 (of 16 rows/instr), chunk = lane&3
  const unsigned short* gbase =
      gsrc + (grow0 + (lane >> 2)) * kDin + (lane & 3) * 8;

  f32x4 acc[4][4];
#pragma unroll
  for (int m = 0; m < 4; ++m)
#pragma unroll
    for (int n = 0; n < 4; ++n) acc[m][n] = (f32x4){0.f, 0.f, 0.f, 0.f};

  const int kg = lane >> 4;   // k-group 0..3 (8 bf16 each)
  const int rl = lane & 15;
  // LDS byte offsets of this lane's fragments (+ m*1024 per m-frag, + mat off)
  const int rdA = (wm * 64 + rl) * 64 + kg * 16;
  const int rdB = (wn * 64 + rl) * 64 + kg * 16;

  // prologue: stage K-step 0 into buf0
  {
    unsigned char* dst = smem + w * 8192;
#pragma unroll
    for (int c = 0; c < 8; ++c)
      gload_lds16(gbase + c * 16 * kDin, dst + c * 1024);
  }
  __syncthreads();

  for (int s = 0; s < 32; ++s) {
    const int p = s & 1;
    if (s < 31) {  // prefetch next K-step into the other buffer
      unsigned char* dst = smem + (p ^ 1) * 32768 + w * 8192;
      const unsigned short* src = gbase + (s + 1) * 32;
#pragma unroll
      for (int c = 0; c < 8; ++c)
        gload_lds16(src + c * 16 * kDin, dst + c * 1024);
    }
    const unsigned char* B0 = smem + p * 32768;
    short8 ah[4], al[4], bh[4], bl[4];
#pragma unroll
    for (int m = 0; m < 4; ++m) {
      ah[m] = *(const short8*)(B0 +         rdA + m * 1024);
      al[m] = *(const short8*)(B0 +  8192 + rdA + m * 1024);
      bh[m] = *(const short8*)(B0 + 16384 + rdB + m * 1024);
      bl[m] = *(const short8*)(B0 + 24576 + rdB + m * 1024);
    }
    __builtin_amdgcn_s_setprio(1);
#pragma unroll
    for (int m = 0; m < 4; ++m)
#pragma unroll
      for (int n = 0; n < 4; ++n) {
        acc[m][n] = mfma_bf16(ah[m], bh[n], acc[m][n]);
        acc[m][n] = mfma_bf16(ah[m], bl[n], acc[m][n]);
        acc[m][n] = mfma_bf16(al[m], bh[n], acc[m][n]);
      }
    __builtin_amdgcn_s_setprio(0);
    __syncthreads();
  }

  // pre-add bias into acc (col depends only on lane)
  float bv[4];
#pragma unroll
  for (int n = 0; n < 4; ++n) bv[n] = bias[j0 + wn * 64 + n * 16 + rl];
#pragma unroll
  for (int m = 0; m < 4; ++m)
#pragma unroll
    for (int n = 0; n < 4; ++n)
#pragma unroll
      for (int r = 0; r < 4; ++r) acc[m][n][r] += bv[n];

  // Epilogue tiles live in buf0's region, fragment-major [kg(4)][row(128)][16B]:
  // Lt at [0,8192) (kg2-3 = zero pad), Mt at [8192,16384).
  {
    unsigned char* p = (tid < 128) ? (smem + 4096 + tid * 32)
                                   : (smem + 12288 + (tid - 128) * 32);
    const us8 z = {0, 0, 0, 0, 0, 0, 0, 0};
    *(us8*)p = z;
    *(us8*)(p + 16) = z;
  }

  for (int t = 0; t < kT; ++t) {
    __syncthreads();  // zeros visible / previous t's reads done
    {
      const int row = tid >> 1, half = tid & 1;
      // Lt (low tile, bf16)
      const us8 lv = *(const us8*)(lowb + ((size_t)t * kM + i0 + row) * kR + half * 8);
      *(us8*)(smem + half * 2048 + row * 16) = lv;
      // Mt (Bm tile, fp32 -> bf16)
      const int ti = tuner[t];
      const float* bp = Bm + ((size_t)ti * kDout + j0 + row) * kR + half * 8;
      const float4 m0 = *(const float4*)bp;
      const float4 m1 = *(const float4*)(bp + 4);
      us8 mv;
      mv[0] = f2bf(m0.x); mv[1] = f2bf(m0.y); mv[2] = f2bf(m0.z); mv[3] = f2bf(m0.w);
      mv[4] = f2bf(m1.x); mv[5] = f2bf(m1.y); mv[6] = f2bf(m1.z); mv[7] = f2bf(m1.w);
      *(us8*)(smem + 8192 + half * 2048 + row * 16) = mv;
    }
    __syncthreads();

    short8 lf[4], mf[4];
#pragma unroll
    for (int m = 0; m < 4; ++m)
      lf[m] = *(const short8*)(smem + kg * 2048 + (wm * 64 + m * 16 + rl) * 16);
#pragma unroll
    for (int n = 0; n < 4; ++n)
      mf[n] = *(const short8*)(smem + 8192 + kg * 2048 + (wn * 64 + n * 16 + rl) * 16);

#pragma unroll
    for (int m = 0; m < 4; ++m)
#pragma unroll
      for (int n = 0; n < 4; ++n) {
        const f32x4 d = mfma_bf16(lf[m], mf[n], acc[m][n]);
        const int r4  = wm * 64 + m * 16 + kg * 4;
        const int col = (int)j0 + wn * 64 + n * 16 + rl;
        const size_t base = ((size_t)t * kM + i0 + r4) * kDout + col;
        out[base]             = d[0];
        out[base + kDout]     = d[1];
        out[base + 2 * kDout] = d[2];
        out[base + 3 * kDout] = d[3];
      }
  }
}

// ---------------------------------------------------------------------------
extern "C" void kernel_launch(void* const* d_in, const int* in_sizes, int n_in,
                              void* d_out, int out_size, void* d_ws, size_t ws_size,
                              hipStream_t stream) {
  const float* x    = (const float*)d_in[0];
  const float* W    = (const float*)d_in[1];
  const float* bias = (const float*)d_in[2];
  const float* lA   = (const float*)d_in[3];
  const float* lB   = (const float*)d_in[4];
  const int*   ti   = (const int*)d_in[5];
  float* out = (float*)d_out;

  unsigned char* ws = (unsigned char*)d_ws;
  unsigned short* xh   = (unsigned short*)(ws + OFF_XH);
  unsigned short* xl   = (unsigned short*)(ws + OFF_XL);
  unsigned short* wh   = (unsigned short*)(ws + OFF_WH);
  unsigned short* wl   = (unsigned short*)(ws + OFF_WL);
  unsigned short* lowb = (unsigned short*)(ws + OFF_LOW);

  cvt_hilo<<<1024, 256, 0, stream>>>(x, W, xh, xl, wh, wl);
  lora_low<<<kM / 32, 256, 0, stream>>>(x, lA, ti, lowb);
  lora_main<<<1024, 256, 0, stream>>>(xh, xl, wh, wl, bias, lB, ti, lowb, out);
}